// Round 5
// baseline (233.454 us; speedup 1.0000x reference)
//
#include <hip/hip_runtime.h>
#include <math.h>

#define CC 64
#define HWN 4096
#define QB 32
#define KSPLIT 4
#define KT 32
#define NCH (HWN / KSPLIT / KT)   // 32 chunks per wave

typedef __attribute__((ext_vector_type(8))) short bf16x8;
typedef __attribute__((ext_vector_type(4))) float f32x4;

// precomputed bf16 operand layouts (fully rewritten by prep_kernel every launch)
__device__ __align__(16) unsigned short g_bgT[4][HWN][CC];  // (bg*sb)^T  [b][k][c]
__device__ __align__(16) unsigned short g_bgN[4][CC][HWN];  // bf16(bg)   [b][c][k]
__device__ __align__(16) unsigned short g_fgT[4][HWN][CC];  // (fg*sf)^T  [b][q][c]

static __device__ __forceinline__ unsigned int f2bf(float x) {   // RNE
  union { float f; unsigned int u; } v; v.f = x;
  return (v.u + 0x7fffu + ((v.u >> 16) & 1u)) >> 16;
}
static __device__ __forceinline__ unsigned int packbf(float lo, float hi) {
  return f2bf(lo) | (f2bf(hi) << 16);
}

// ---- prep: fused column norms + bf16 operand layouts (verified in r3) ----
__global__ __launch_bounds__(256) void prep_kernel(const float* __restrict__ bg,
                                                   const float* __restrict__ fg) {
  __shared__ float lds[64 * 65];   // [k][c], stride 65 (2-way banks)
  const int bid = blockIdx.x;
  const int kt = bid & 63, b = (bid >> 6) & 3, which = bid >> 8;
  const float* src = (which ? fg : bg) + (size_t)b * CC * HWN + kt * 64;
  const int tid = threadIdx.x;

  {
    int c = tid >> 2, k0 = (tid & 3) * 16;
#pragma unroll
    for (int j4 = 0; j4 < 4; ++j4) {
      float4 v = *(const float4*)(src + (size_t)c * HWN + k0 + 4 * j4);
      lds[(k0 + 4 * j4 + 0) * 65 + c] = v.x;
      lds[(k0 + 4 * j4 + 1) * 65 + c] = v.y;
      lds[(k0 + 4 * j4 + 2) * 65 + c] = v.z;
      lds[(k0 + 4 * j4 + 3) * 65 + c] = v.w;
    }
  }
  __syncthreads();

  const int k = tid >> 2, u = tid & 3;
  float ss = 0.f;
#pragma unroll
  for (int j = 0; j < 16; ++j) {
    float v = lds[k * 65 + u * 16 + j];
    ss = fmaf(v, v, ss);
  }
  ss += __shfl_xor(ss, 1, 64);
  ss += __shfl_xor(ss, 2, 64);
  const float s = 1.0f / fmaxf(sqrtf(ss), 1e-12f);

  {
    unsigned int* gT32 = (unsigned int*)(which ? &g_fgT[0][0][0] : &g_bgT[0][0][0]);
    size_t R = (size_t)b * HWN + kt * 64 + k;
    unsigned int w8[8];
#pragma unroll
    for (int i = 0; i < 8; ++i) {
      int c2 = u * 16 + 2 * i;
      w8[i] = packbf(lds[k * 65 + c2] * s, lds[k * 65 + c2 + 1] * s);
    }
    *(uint4*)&gT32[R * 32 + u * 8]     = make_uint4(w8[0], w8[1], w8[2], w8[3]);
    *(uint4*)&gT32[R * 32 + u * 8 + 4] = make_uint4(w8[4], w8[5], w8[6], w8[7]);
  }

  if (which == 0) {
    unsigned int* gN32 = (unsigned int*)&g_bgN[0][0][0];
    int cN = tid >> 2, vN = tid & 3;
    unsigned int n8[8];
#pragma unroll
    for (int i = 0; i < 8; ++i) {
      int kk = vN * 16 + 2 * i;
      n8[i] = packbf(lds[kk * 65 + cN], lds[(kk + 1) * 65 + cN]);
    }
    size_t RN = ((size_t)b * CC + cN) * (HWN / 2) + kt * 32 + vN * 8;
    *(uint4*)&gN32[RN]     = make_uint4(n8[0], n8[1], n8[2], n8[3]);
    *(uint4*)&gN32[RN + 4] = make_uint4(n8[4], n8[5], n8[6], n8[7]);
  }
}

// ---- copy fg*(1-m) -> out everywhere + build compacted masked-query index ----
// ONE float4 per thread: 262144 float4 total -> grid 1024 x 256 (r4 crash: was 4096)
__global__ __launch_bounds__(256) void copyidx_kernel(const float* __restrict__ fg,
                                                      const float* __restrict__ mask,
                                                      float* __restrict__ out,
                                                      int* __restrict__ cnt,
                                                      int* __restrict__ idx) {
  int t = blockIdx.x * 256 + threadIdx.x;   // float4 index, 0..262143
  int q4 = t & 1023;
  int bc = t >> 10;                         // 0..255 = b*64 + c
  int b = bc >> 6;
  float4 m = *(const float4*)(mask + (b << 12) + q4 * 4);
  float4 f = *(const float4*)(fg + (size_t)t * 4);
  float4 o;
  o.x = f.x * (1.f - m.x); o.y = f.y * (1.f - m.y);
  o.z = f.z * (1.f - m.z); o.w = f.w * (1.f - m.w);
  *(float4*)(out + (size_t)t * 4) = o;
  if ((bc & 63) == 0) {   // one thread per (b, q4)
#pragma unroll
    for (int e = 0; e < 4; ++e) {
      float mv = (&m.x)[e];
      if (mv > 0.5f) {
        int slot = atomicAdd(&cnt[b], 1);
        idx[(b << 12) + slot] = q4 * 4 + e;
      }
    }
  }
}

// ---- flash attention on compacted queries: bf16 MFMA, prefetch-pipelined ----
// LDS: [0,32768)  bgT staging double-buffer (2 x [4ks][32k][64c] swizzled, 16 KB each)
//      [32768,43008) P per wave [16q][40k] ushort
//      [43008,43520) mL [8w][16q] f32
//      epilogue aliases [0,34816) as mO [4ks][64c][34]  (after final barrier)
#define SMEM_BYTES 43520
__global__ __launch_bounds__(512, 2) void attn_kernel(const int* __restrict__ cntp,
                                                      const int* __restrict__ idx,
                                                      float* __restrict__ out) {
  const int id = blockIdx.x;
  const int b = (id >> 1) & 3;              // XCD-affine: batch pinned per XCD pair
  const int qblk = (id >> 3) * 2 + (id & 1);
  const int q0 = qblk * QB;
  const int cnt = cntp[b];
  if (q0 >= cnt) return;

  __shared__ __align__(16) char smem[SMEM_BYTES];
  const int tid = threadIdx.x;
  const int lane = tid & 63;
  const int w = tid >> 6;     // 0..7
  const int qf = w & 1;       // q-half (16 q)
  const int ks = w >> 1;      // K-split 0..3 (1024 keys each)
  const int m16 = lane & 15;
  const int quad = lane >> 4;
  const int* idxb = idx + (b << 12);

  // score B-fragments: gathered masked-query rows (per-lane row read anyway)
  const int qrow = idxb[min(q0 + qf * 16 + m16, cnt - 1)];
  const bf16x8 Bf0 = *(const bf16x8*)&g_fgT[b][qrow][quad * 8];
  const bf16x8 Bf1 = *(const bf16x8*)&g_fgT[b][qrow][32 + quad * 8];

  // bgT staging: 128 threads per ks stage 4 KB/chunk; XOR-swizzled global source
  const unsigned short* srcT0[2];
  int ubv[2];
#pragma unroll
  for (int t = 0; t < 2; ++t) {
    int ub = (t * 2 + qf) * 64;
    ubv[t] = ub;
    int uT = ub + lane;
    int kk = uT >> 3, j = (uT & 7) ^ (kk & 7);
    srcT0[t] = &g_bgT[b][ks * 1024 + kk][j * 8];
  }

  auto fetch = [&](int nit) {
    char* base = smem + (nit & 1) * 16384 + ks * 4096;
#pragma unroll
    for (int t = 0; t < 2; ++t)
      __builtin_amdgcn_global_load_lds(
          (const __attribute__((address_space(1))) unsigned int*)(srcT0[t] + (size_t)nit * (KT * CC)),
          (__attribute__((address_space(3))) unsigned int*)(base + ubv[t] * 16), 16, 0, 0);
  };

  unsigned short* P = (unsigned short*)(smem + 32768 + w * 1280);  // [16q][40k]
  float* mL = (float*)(smem + 43008);

  float l_run = 0.f;
  f32x4 O[4];
#pragma unroll
  for (int t = 0; t < 4; ++t) O[t] = (f32x4){0.f, 0.f, 0.f, 0.f};

  fetch(0);   // prologue

  for (int it = 0; it < NCH; ++it) {
    __syncthreads();                 // drains fetch(it) (vmcnt0) + protects buffer reuse
    if (it + 1 < NCH) fetch(it + 1); // in flight across the whole compute phase

    const char* baseT = smem + (it & 1) * 16384 + ks * 4096;
    const int kb = ks * 1024 + it * KT;

    // scores S[32k][16q]
    f32x4 S[2];
#pragma unroll
    for (int i = 0; i < 2; ++i) {
      int kk = 16 * i + m16;
      bf16x8 A0 = *(const bf16x8*)(baseT + kk * 128 + ((quad ^ (kk & 7)) * 16));
      bf16x8 A1 = *(const bf16x8*)(baseT + kk * 128 + (((4 + quad) ^ (kk & 7)) * 16));
      f32x4 acc = {0.f, 0.f, 0.f, 0.f};
      acc = __builtin_amdgcn_mfma_f32_16x16x32_bf16(A0, Bf0, acc, 0, 0, 0);
      acc = __builtin_amdgcn_mfma_f32_16x16x32_bf16(A1, Bf1, acc, 0, 0, 0);
      S[i] = acc;
    }

    // fixed-max softmax (cosine scores, |s|<=1): p = exp(s-1), no running max
    float pe[2][4];
    float ps = 0.f;
#pragma unroll
    for (int i = 0; i < 2; ++i)
#pragma unroll
      for (int r = 0; r < 4; ++r) {
        pe[i][r] = __expf(S[i][r] - 1.0f);
        ps += pe[i][r];
      }
    ps += __shfl_xor(ps, 16, 64);
    ps += __shfl_xor(ps, 32, 64);
    l_run += ps;

    // P -> per-wave LDS [q][k] bf16 (no barrier: wave-private region)
#pragma unroll
    for (int i = 0; i < 2; ++i) {
      union { float f; unsigned int u; } x0, x1, x2, x3;
      x0.f = pe[i][0]; x1.f = pe[i][1]; x2.f = pe[i][2]; x3.f = pe[i][3];
      unsigned int p01 = __builtin_amdgcn_perm(x1.u + 0x8000u, x0.u + 0x8000u, 0x07060302u);
      unsigned int p23 = __builtin_amdgcn_perm(x3.u + 0x8000u, x2.u + 0x8000u, 0x07060302u);
      *(uint2*)&P[m16 * 40 + 16 * i + quad * 4] = make_uint2(p01, p23);
    }

    // PV: O[c][q] += bg[c][k] · P[k][q]; A-fragments direct from global (L2-hot)
    bf16x8 Pf = *(const bf16x8*)&P[m16 * 40 + quad * 8];
#pragma unroll
    for (int t = 0; t < 4; ++t) {
      bf16x8 A = *(const bf16x8*)&g_bgN[b][16 * t + m16][kb + quad * 8];
      O[t] = __builtin_amdgcn_mfma_f32_16x16x32_bf16(A, Pf, O[t], 0, 0, 0);
    }
  }

  // ---- merge 4 K-splits + scatter epilogue (mO aliases staging after barrier) ----
  __syncthreads();
  float* mO = (float*)smem;   // [4ks][64c][34]
  if (quad == 0) mL[w * 16 + m16] = l_run;
#pragma unroll
  for (int t = 0; t < 4; ++t)
#pragma unroll
    for (int r = 0; r < 4; ++r)
      mO[(ks * 64 + 16 * t + quad * 4 + r) * 34 + qf * 16 + m16] = O[t][r];
  __syncthreads();

  float* outB = out + (size_t)b * CC * HWN;
#pragma unroll
  for (int rep = 0; rep < 4; ++rep) {
    int e = tid + rep * 512;          // 0..2047
    int c = e >> 5, q32 = e & 31;
    int qi = idxb[min(q0 + q32, cnt - 1)];
    int qh = q32 >> 4, qm = q32 & 15;
    float L = mL[(0 + qh) * 16 + qm] + mL[(2 + qh) * 16 + qm] +
              mL[(4 + qh) * 16 + qm] + mL[(6 + qh) * 16 + qm];
    float acc = mO[(0 * 64 + c) * 34 + q32] + mO[(1 * 64 + c) * 34 + q32] +
                mO[(2 * 64 + c) * 34 + q32] + mO[(3 * 64 + c) * 34 + q32];
    outB[(size_t)c * HWN + qi] = acc / L;   // masked cols: out = attended exactly
  }
}

extern "C" void kernel_launch(void* const* d_in, const int* in_sizes, int n_in,
                              void* d_out, int out_size, void* d_ws, size_t ws_size,
                              hipStream_t stream) {
  const float* background = (const float*)d_in[0];
  const float* foreground = (const float*)d_in[1];
  const float* mask       = (const float*)d_in[2];
  float* out = (float*)d_out;
  int* cnt = (int*)d_ws;              // 4 ints (first 64 B zeroed)
  int* idx = (int*)d_ws + 16;         // [4][4096] ints (64 KB)
  hipMemsetAsync(d_ws, 0, 64, stream);
  prep_kernel<<<512, 256, 0, stream>>>(background, foreground);
  copyidx_kernel<<<1024, 256, 0, stream>>>(foreground, mask, out, cnt, idx);
  attn_kernel<<<512, 512, 0, stream>>>(cnt, idx, out);
}

// Round 6
// 139.859 us; speedup vs baseline: 1.6692x; 1.6692x over previous
//
#include <hip/hip_runtime.h>
#include <math.h>

#define CC 64
#define HWN 4096
#define QB 32
#define KSPLIT 4
#define KT 32
#define NCH (HWN / KSPLIT / KT)   // 32 chunks per wave

typedef __attribute__((ext_vector_type(8))) short bf16x8;
typedef __attribute__((ext_vector_type(4))) float f32x4;

// precomputed bf16 operand layouts (fully rewritten by prep_kernel every launch)
__device__ __align__(16) unsigned short g_bgT[4][HWN][CC];  // (bg*sb)^T  [b][k][c]
__device__ __align__(16) unsigned short g_bgN[4][CC][HWN];  // bf16(bg)   [b][c][k]
__device__ __align__(16) unsigned short g_fgT[4][HWN][CC];  // (fg*sf)^T  [b][q][c]

static __device__ __forceinline__ unsigned int f2bf(float x) {   // RNE
  union { float f; unsigned int u; } v; v.f = x;
  return (v.u + 0x7fffu + ((v.u >> 16) & 1u)) >> 16;
}
static __device__ __forceinline__ unsigned int packbf(float lo, float hi) {
  return f2bf(lo) | (f2bf(hi) << 16);
}

// ---- prep: fused column norms + bf16 operand layouts (verified in r3) ----
__global__ __launch_bounds__(256) void prep_kernel(const float* __restrict__ bg,
                                                   const float* __restrict__ fg) {
  __shared__ float lds[64 * 65];   // [k][c], stride 65 (2-way banks)
  const int bid = blockIdx.x;
  const int kt = bid & 63, b = (bid >> 6) & 3, which = bid >> 8;
  const float* src = (which ? fg : bg) + (size_t)b * CC * HWN + kt * 64;
  const int tid = threadIdx.x;

  {
    int c = tid >> 2, k0 = (tid & 3) * 16;
#pragma unroll
    for (int j4 = 0; j4 < 4; ++j4) {
      float4 v = *(const float4*)(src + (size_t)c * HWN + k0 + 4 * j4);
      lds[(k0 + 4 * j4 + 0) * 65 + c] = v.x;
      lds[(k0 + 4 * j4 + 1) * 65 + c] = v.y;
      lds[(k0 + 4 * j4 + 2) * 65 + c] = v.z;
      lds[(k0 + 4 * j4 + 3) * 65 + c] = v.w;
    }
  }
  __syncthreads();

  const int k = tid >> 2, u = tid & 3;
  float ss = 0.f;
#pragma unroll
  for (int j = 0; j < 16; ++j) {
    float v = lds[k * 65 + u * 16 + j];
    ss = fmaf(v, v, ss);
  }
  ss += __shfl_xor(ss, 1, 64);
  ss += __shfl_xor(ss, 2, 64);
  const float s = 1.0f / fmaxf(sqrtf(ss), 1e-12f);

  {
    unsigned int* gT32 = (unsigned int*)(which ? &g_fgT[0][0][0] : &g_bgT[0][0][0]);
    size_t R = (size_t)b * HWN + kt * 64 + k;
    unsigned int w8[8];
#pragma unroll
    for (int i = 0; i < 8; ++i) {
      int c2 = u * 16 + 2 * i;
      w8[i] = packbf(lds[k * 65 + c2] * s, lds[k * 65 + c2 + 1] * s);
    }
    *(uint4*)&gT32[R * 32 + u * 8]     = make_uint4(w8[0], w8[1], w8[2], w8[3]);
    *(uint4*)&gT32[R * 32 + u * 8 + 4] = make_uint4(w8[4], w8[5], w8[6], w8[7]);
  }

  if (which == 0) {
    unsigned int* gN32 = (unsigned int*)&g_bgN[0][0][0];
    int cN = tid >> 2, vN = tid & 3;
    unsigned int n8[8];
#pragma unroll
    for (int i = 0; i < 8; ++i) {
      int kk = vN * 16 + 2 * i;
      n8[i] = packbf(lds[kk * 65 + cN], lds[(kk + 1) * 65 + cN]);
    }
    size_t RN = ((size_t)b * CC + cN) * (HWN / 2) + kt * 32 + vN * 8;
    *(uint4*)&gN32[RN]     = make_uint4(n8[0], n8[1], n8[2], n8[3]);
    *(uint4*)&gN32[RN + 4] = make_uint4(n8[4], n8[5], n8[6], n8[7]);
  }
}

// ---- compact: deterministic prefix-sum of binary mask -> sorted index list ----
// 4 blocks (one per batch) x 1024 threads, 4 mask values per thread. No atomics.
__global__ __launch_bounds__(1024) void compact_kernel(const float* __restrict__ mask,
                                                       int* __restrict__ cnt,
                                                       int* __restrict__ idx) {
  __shared__ int wsum[16], wbase[16];
  const int b = blockIdx.x;
  const int tid = threadIdx.x;
  const int lane = tid & 63, wv = tid >> 6;
  float4 m = *(const float4*)(mask + (b << 12) + tid * 4);
  const int p0 = m.x > 0.5f, p1 = m.y > 0.5f, p2 = m.z > 0.5f, p3 = m.w > 0.5f;
  const int ls = p0 + p1 + p2 + p3;
  int s = ls;
#pragma unroll
  for (int off = 1; off < 64; off <<= 1) {     // wave inclusive scan
    int v = __shfl_up(s, off, 64);
    if (lane >= off) s += v;
  }
  if (lane == 63) wsum[wv] = s;
  __syncthreads();
  if (tid == 0) {
    int acc = 0;
#pragma unroll
    for (int i = 0; i < 16; ++i) { wbase[i] = acc; acc += wsum[i]; }
    cnt[b] = acc;
  }
  __syncthreads();
  int base = wbase[wv] + s - ls;               // exclusive prefix
  int* ib = idx + (b << 12);
  const int q = tid * 4;
  if (p0) ib[base++] = q;
  if (p1) ib[base++] = q + 1;
  if (p2) ib[base++] = q + 2;
  if (p3) ib[base++] = q + 3;
}

// ---- flash attention on compacted queries: bf16 MFMA, prefetch-pipelined ----
// LDS: [0,32768)  bgT staging double-buffer (2 x [4ks][32k][64c] swizzled, 16 KB each)
//      [32768,43008) P per wave [16q][40k] ushort
//      [43008,43520) mL [8w][16q] f32
//      epilogue aliases [0,34816) as mO [4ks][64c][34]  (after final barrier)
#define SMEM_BYTES 43520
__global__ __launch_bounds__(512, 2) void attn_kernel(const int* __restrict__ cntp,
                                                      const int* __restrict__ idx,
                                                      float* __restrict__ out) {
  const int id = blockIdx.x;
  const int b = (id >> 1) & 3;              // XCD-affine: batch pinned per XCD pair
  const int qblk = (id >> 3) * 2 + (id & 1);
  const int q0 = qblk * QB;
  const int cnt = cntp[b];
  if (q0 >= cnt) return;

  __shared__ __align__(16) char smem[SMEM_BYTES];
  const int tid = threadIdx.x;
  const int lane = tid & 63;
  const int w = tid >> 6;     // 0..7
  const int qf = w & 1;       // q-half (16 q)
  const int ks = w >> 1;      // K-split 0..3 (1024 keys each)
  const int m16 = lane & 15;
  const int quad = lane >> 4;
  const int* idxb = idx + (b << 12);

  // score B-fragments: gathered masked-query rows (sorted -> good L2 locality)
  const int qrow = idxb[min(q0 + qf * 16 + m16, cnt - 1)];
  const bf16x8 Bf0 = *(const bf16x8*)&g_fgT[b][qrow][quad * 8];
  const bf16x8 Bf1 = *(const bf16x8*)&g_fgT[b][qrow][32 + quad * 8];

  // bgT staging: 128 threads per ks stage 4 KB/chunk; XOR-swizzled global source
  const unsigned short* srcT0[2];
  int ubv[2];
#pragma unroll
  for (int t = 0; t < 2; ++t) {
    int ub = (t * 2 + qf) * 64;
    ubv[t] = ub;
    int uT = ub + lane;
    int kk = uT >> 3, j = (uT & 7) ^ (kk & 7);
    srcT0[t] = &g_bgT[b][ks * 1024 + kk][j * 8];
  }

  auto fetch = [&](int nit) {
    char* base = smem + (nit & 1) * 16384 + ks * 4096;
#pragma unroll
    for (int t = 0; t < 2; ++t)
      __builtin_amdgcn_global_load_lds(
          (const __attribute__((address_space(1))) unsigned int*)(srcT0[t] + (size_t)nit * (KT * CC)),
          (__attribute__((address_space(3))) unsigned int*)(base + ubv[t] * 16), 16, 0, 0);
  };

  unsigned short* P = (unsigned short*)(smem + 32768 + w * 1280);  // [16q][40k]
  float* mL = (float*)(smem + 43008);

  float l_run = 0.f;
  f32x4 O[4];
#pragma unroll
  for (int t = 0; t < 4; ++t) O[t] = (f32x4){0.f, 0.f, 0.f, 0.f};

  fetch(0);   // prologue

  for (int it = 0; it < NCH; ++it) {
    __syncthreads();                 // drains fetch(it) (vmcnt0) + protects buffer reuse
    if (it + 1 < NCH) fetch(it + 1); // in flight across the whole compute phase

    const char* baseT = smem + (it & 1) * 16384 + ks * 4096;
    const int kb = ks * 1024 + it * KT;

    // scores S[32k][16q]
    f32x4 S[2];
#pragma unroll
    for (int i = 0; i < 2; ++i) {
      int kk = 16 * i + m16;
      bf16x8 A0 = *(const bf16x8*)(baseT + kk * 128 + ((quad ^ (kk & 7)) * 16));
      bf16x8 A1 = *(const bf16x8*)(baseT + kk * 128 + (((4 + quad) ^ (kk & 7)) * 16));
      f32x4 acc = {0.f, 0.f, 0.f, 0.f};
      acc = __builtin_amdgcn_mfma_f32_16x16x32_bf16(A0, Bf0, acc, 0, 0, 0);
      acc = __builtin_amdgcn_mfma_f32_16x16x32_bf16(A1, Bf1, acc, 0, 0, 0);
      S[i] = acc;
    }

    // fixed-max softmax (cosine scores, |s|<=1): p = exp(s-1), no running max
    float pe[2][4];
    float ps = 0.f;
#pragma unroll
    for (int i = 0; i < 2; ++i)
#pragma unroll
      for (int r = 0; r < 4; ++r) {
        pe[i][r] = __expf(S[i][r] - 1.0f);
        ps += pe[i][r];
      }
    ps += __shfl_xor(ps, 16, 64);
    ps += __shfl_xor(ps, 32, 64);
    l_run += ps;

    // P -> per-wave LDS [q][k] bf16 (no barrier: wave-private region)
#pragma unroll
    for (int i = 0; i < 2; ++i) {
      union { float f; unsigned int u; } x0, x1, x2, x3;
      x0.f = pe[i][0]; x1.f = pe[i][1]; x2.f = pe[i][2]; x3.f = pe[i][3];
      unsigned int p01 = __builtin_amdgcn_perm(x1.u + 0x8000u, x0.u + 0x8000u, 0x07060302u);
      unsigned int p23 = __builtin_amdgcn_perm(x3.u + 0x8000u, x2.u + 0x8000u, 0x07060302u);
      *(uint2*)&P[m16 * 40 + 16 * i + quad * 4] = make_uint2(p01, p23);
    }

    // PV: O[c][q] += bg[c][k] · P[k][q]; A-fragments direct from global (L2-hot)
    bf16x8 Pf = *(const bf16x8*)&P[m16 * 40 + quad * 8];
#pragma unroll
    for (int t = 0; t < 4; ++t) {
      bf16x8 A = *(const bf16x8*)&g_bgN[b][16 * t + m16][kb + quad * 8];
      O[t] = __builtin_amdgcn_mfma_f32_16x16x32_bf16(A, Pf, O[t], 0, 0, 0);
    }
  }

  // ---- merge 4 K-splits + scatter epilogue (mO aliases staging after barrier) ----
  __syncthreads();
  float* mO = (float*)smem;   // [4ks][64c][34]
  if (quad == 0) mL[w * 16 + m16] = l_run;
#pragma unroll
  for (int t = 0; t < 4; ++t)
#pragma unroll
    for (int r = 0; r < 4; ++r)
      mO[(ks * 64 + 16 * t + quad * 4 + r) * 34 + qf * 16 + m16] = O[t][r];
  __syncthreads();

  float* outB = out + (size_t)b * CC * HWN;
#pragma unroll
  for (int rep = 0; rep < 4; ++rep) {
    int e = tid + rep * 512;          // 0..2047
    int c = e >> 5, q32 = e & 31;
    int qi = idxb[min(q0 + q32, cnt - 1)];
    int qh = q32 >> 4, qm = q32 & 15;
    float L = mL[(0 + qh) * 16 + qm] + mL[(2 + qh) * 16 + qm] +
              mL[(4 + qh) * 16 + qm] + mL[(6 + qh) * 16 + qm];
    float acc = mO[(0 * 64 + c) * 34 + q32] + mO[(1 * 64 + c) * 34 + q32] +
                mO[(2 * 64 + c) * 34 + q32] + mO[(3 * 64 + c) * 34 + q32];
    outB[(size_t)c * HWN + qi] = acc / L;   // masked cols: out = attended exactly
  }
}

extern "C" void kernel_launch(void* const* d_in, const int* in_sizes, int n_in,
                              void* d_out, int out_size, void* d_ws, size_t ws_size,
                              hipStream_t stream) {
  const float* background = (const float*)d_in[0];
  const float* foreground = (const float*)d_in[1];
  const float* mask       = (const float*)d_in[2];
  float* out = (float*)d_out;
  int* cnt = (int*)d_ws;              // 4 ints
  int* idx = (int*)d_ws + 16;         // [4][4096] ints (64 KB)
  // out = fg everywhere (binary mask: unmasked cols need fg; masked cols are
  // fully overwritten by attn's scatter epilogue)
  hipMemcpyAsync(out, foreground, (size_t)4 * CC * HWN * sizeof(float),
                 hipMemcpyDeviceToDevice, stream);
  prep_kernel<<<512, 256, 0, stream>>>(background, foreground);
  compact_kernel<<<4, 1024, 0, stream>>>(mask, cnt, idx);
  attn_kernel<<<512, 512, 0, stream>>>(cnt, idx, out);
}

// Round 7
// 138.689 us; speedup vs baseline: 1.6833x; 1.0084x over previous
//
#include <hip/hip_runtime.h>
#include <math.h>

#define CC 64
#define HWN 4096
#define QB 16            // queries per block (one 16-q MFMA tile)
#define KSPLIT 4
#define KT 32
#define NCH (HWN / KSPLIT / KT)   // 32 chunks per wave

typedef __attribute__((ext_vector_type(8))) short bf16x8;
typedef __attribute__((ext_vector_type(4))) float f32x4;

// precomputed bf16 operand layouts (fully rewritten by prep_kernel every launch)
__device__ __align__(16) unsigned short g_bgT[4][HWN][CC];  // (bg*sb)^T  [b][k][c]
__device__ __align__(16) unsigned short g_bgN[4][CC][HWN];  // bf16(bg)   [b][c][k]
__device__ __align__(16) unsigned short g_fgT[4][HWN][CC];  // (fg*sf)^T  [b][q][c]

static __device__ __forceinline__ unsigned int f2bf(float x) {   // RNE
  union { float f; unsigned int u; } v; v.f = x;
  return (v.u + 0x7fffu + ((v.u >> 16) & 1u)) >> 16;
}
static __device__ __forceinline__ unsigned int packbf(float lo, float hi) {
  return f2bf(lo) | (f2bf(hi) << 16);
}

// ---- prep: fused column norms + bf16 operand layouts (verified r3) ----
__global__ __launch_bounds__(256) void prep_kernel(const float* __restrict__ bg,
                                                   const float* __restrict__ fg) {
  __shared__ float lds[64 * 65];   // [k][c], stride 65 (2-way banks)
  const int bid = blockIdx.x;
  const int kt = bid & 63, b = (bid >> 6) & 3, which = bid >> 8;
  const float* src = (which ? fg : bg) + (size_t)b * CC * HWN + kt * 64;
  const int tid = threadIdx.x;

  {
    int c = tid >> 2, k0 = (tid & 3) * 16;
#pragma unroll
    for (int j4 = 0; j4 < 4; ++j4) {
      float4 v = *(const float4*)(src + (size_t)c * HWN + k0 + 4 * j4);
      lds[(k0 + 4 * j4 + 0) * 65 + c] = v.x;
      lds[(k0 + 4 * j4 + 1) * 65 + c] = v.y;
      lds[(k0 + 4 * j4 + 2) * 65 + c] = v.z;
      lds[(k0 + 4 * j4 + 3) * 65 + c] = v.w;
    }
  }
  __syncthreads();

  const int k = tid >> 2, u = tid & 3;
  float ss = 0.f;
#pragma unroll
  for (int j = 0; j < 16; ++j) {
    float v = lds[k * 65 + u * 16 + j];
    ss = fmaf(v, v, ss);
  }
  ss += __shfl_xor(ss, 1, 64);
  ss += __shfl_xor(ss, 2, 64);
  const float s = 1.0f / fmaxf(sqrtf(ss), 1e-12f);

  {
    unsigned int* gT32 = (unsigned int*)(which ? &g_fgT[0][0][0] : &g_bgT[0][0][0]);
    size_t R = (size_t)b * HWN + kt * 64 + k;
    unsigned int w8[8];
#pragma unroll
    for (int i = 0; i < 8; ++i) {
      int c2 = u * 16 + 2 * i;
      w8[i] = packbf(lds[k * 65 + c2] * s, lds[k * 65 + c2 + 1] * s);
    }
    *(uint4*)&gT32[R * 32 + u * 8]     = make_uint4(w8[0], w8[1], w8[2], w8[3]);
    *(uint4*)&gT32[R * 32 + u * 8 + 4] = make_uint4(w8[4], w8[5], w8[6], w8[7]);
  }

  if (which == 0) {
    unsigned int* gN32 = (unsigned int*)&g_bgN[0][0][0];
    int cN = tid >> 2, vN = tid & 3;
    unsigned int n8[8];
#pragma unroll
    for (int i = 0; i < 8; ++i) {
      int kk = vN * 16 + 2 * i;
      n8[i] = packbf(lds[kk * 65 + cN], lds[(kk + 1) * 65 + cN]);
    }
    size_t RN = ((size_t)b * CC + cN) * (HWN / 2) + kt * 32 + vN * 8;
    *(uint4*)&gN32[RN]     = make_uint4(n8[0], n8[1], n8[2], n8[3]);
    *(uint4*)&gN32[RN + 4] = make_uint4(n8[4], n8[5], n8[6], n8[7]);
  }
}

// ---- compact: deterministic prefix-sum of binary mask -> sorted index list ----
__global__ __launch_bounds__(1024) void compact_kernel(const float* __restrict__ mask,
                                                       int* __restrict__ cnt,
                                                       int* __restrict__ idx) {
  __shared__ int wsum[16], wbase[16];
  const int b = blockIdx.x;
  const int tid = threadIdx.x;
  const int lane = tid & 63, wv = tid >> 6;
  float4 m = *(const float4*)(mask + (b << 12) + tid * 4);
  const int p0 = m.x > 0.5f, p1 = m.y > 0.5f, p2 = m.z > 0.5f, p3 = m.w > 0.5f;
  const int ls = p0 + p1 + p2 + p3;
  int s = ls;
#pragma unroll
  for (int off = 1; off < 64; off <<= 1) {
    int v = __shfl_up(s, off, 64);
    if (lane >= off) s += v;
  }
  if (lane == 63) wsum[wv] = s;
  __syncthreads();
  if (tid == 0) {
    int acc = 0;
#pragma unroll
    for (int i = 0; i < 16; ++i) { wbase[i] = acc; acc += wsum[i]; }
    cnt[b] = acc;
  }
  __syncthreads();
  int base = wbase[wv] + s - ls;
  int* ib = idx + (b << 12);
  const int q = tid * 4;
  if (p0) ib[base++] = q;
  if (p1) ib[base++] = q + 1;
  if (p2) ib[base++] = q + 2;
  if (p3) ib[base++] = q + 3;
}

// ---- flash attention, persistent all-active grid, reg-prefetched PV ----
// 512 blocks x 256 thr (4 waves = 4 K-splits, 16 q/block), every block active.
// LDS: [0,32768)  bgT dbuf: 2 x [4ks][32k][64c] swizzled (16 KB each)
//      [32768,37888) P per wave [16q][40k] ushort
//      [37888,38144) mL [4ks][16q] f32
//      epilogue aliases [0,18432) as mO [4ks][64c][18]
#define SMEM_BYTES 38144
__global__ __launch_bounds__(256, 2) void attn_kernel(const int* __restrict__ cntp,
                                                      const int* __restrict__ idx,
                                                      float* __restrict__ out) {
  const int id = blockIdx.x;
  const int b = id & 3;                 // batches interleaved across dispatch order
  const int r0 = id >> 2;               // 0..127
  const int cnt = cntp[b];
  const int ntiles = (cnt + QB - 1) >> 4;

  __shared__ __align__(16) char smem[SMEM_BYTES];
  const int tid = threadIdx.x;
  const int lane = tid & 63;
  const int ks = tid >> 6;              // wave = K-split 0..3 (1024 keys each)
  const int m16 = lane & 15;
  const int quad = lane >> 4;
  const int* idxb = idx + (b << 12);

  // staging source swizzle (4 x 16B granules per lane per chunk)
  const unsigned short* srcT0[4];
#pragma unroll
  for (int t = 0; t < 4; ++t) {
    int uT = t * 64 + lane;
    int kk = uT >> 3, j = (uT & 7) ^ (kk & 7);
    srcT0[t] = &g_bgT[b][ks * 1024 + kk][j * 8];
  }
  auto fetch = [&](int nit) {
    char* base = smem + (nit & 1) * 16384 + ks * 4096;
#pragma unroll
    for (int t = 0; t < 4; ++t)
      __builtin_amdgcn_global_load_lds(
          (const __attribute__((address_space(1))) unsigned int*)(srcT0[t] + (size_t)nit * (KT * CC)),
          (__attribute__((address_space(3))) unsigned int*)(base + t * 1024), 16, 0, 0);
  };

  unsigned short* P = (unsigned short*)(smem + 32768 + ks * 1280);  // [16q][40k]
  float* mL = (float*)(smem + 37888);
  float* outB = out + (size_t)b * CC * HWN;

  for (int r = r0; r < ntiles; r += 128) {
    const int q0 = r * QB;
    // score B-fragments: gathered masked-query rows (sorted idx -> L2 locality)
    const int qrow = idxb[min(q0 + m16, cnt - 1)];
    const bf16x8 Bf0 = *(const bf16x8*)&g_fgT[b][qrow][quad * 8];
    const bf16x8 Bf1 = *(const bf16x8*)&g_fgT[b][qrow][32 + quad * 8];

    float l_run = 0.f;
    f32x4 O[4];
#pragma unroll
    for (int t = 0; t < 4; ++t) O[t] = (f32x4){0.f, 0.f, 0.f, 0.f};

    __syncthreads();   // previous tile's epilogue reads of mO (aliases staging) done
    fetch(0);

    for (int it = 0; it < NCH; ++it) {
      __syncthreads();               // drains fetch(it); buffer (it&1) now valid
      const int kb = ks * 1024 + it * KT;

      // PV A-operands: register prefetch issued FIRST (so their waitcnt
      // leaves the subsequent global_load_lds prefetch in flight), landing
      // during score MFMA + softmax.
      bf16x8 Apv[4];
#pragma unroll
      for (int t = 0; t < 4; ++t)
        Apv[t] = *(const bf16x8*)&g_bgN[b][16 * t + m16][kb + quad * 8];

      if (it + 1 < NCH) fetch(it + 1);   // in flight across the compute phase

      const char* baseT = smem + (it & 1) * 16384 + ks * 4096;

      // scores S[32k][16q]
      f32x4 S[2];
#pragma unroll
      for (int i = 0; i < 2; ++i) {
        int kk = 16 * i + m16;
        bf16x8 A0 = *(const bf16x8*)(baseT + kk * 128 + ((quad ^ (kk & 7)) * 16));
        bf16x8 A1 = *(const bf16x8*)(baseT + kk * 128 + (((4 + quad) ^ (kk & 7)) * 16));
        f32x4 acc = {0.f, 0.f, 0.f, 0.f};
        acc = __builtin_amdgcn_mfma_f32_16x16x32_bf16(A0, Bf0, acc, 0, 0, 0);
        acc = __builtin_amdgcn_mfma_f32_16x16x32_bf16(A1, Bf1, acc, 0, 0, 0);
        S[i] = acc;
      }

      // fixed-max softmax (cosine scores, |s|<=1): p = exp(s-1)
      float pe[2][4];
      float ps = 0.f;
#pragma unroll
      for (int i = 0; i < 2; ++i)
#pragma unroll
        for (int rr = 0; rr < 4; ++rr) {
          pe[i][rr] = __expf(S[i][rr] - 1.0f);
          ps += pe[i][rr];
        }
      ps += __shfl_xor(ps, 16, 64);
      ps += __shfl_xor(ps, 32, 64);
      l_run += ps;

      // P -> per-wave LDS [q][k] bf16 (wave-private region, no barrier)
#pragma unroll
      for (int i = 0; i < 2; ++i) {
        union { float f; unsigned int u; } x0, x1, x2, x3;
        x0.f = pe[i][0]; x1.f = pe[i][1]; x2.f = pe[i][2]; x3.f = pe[i][3];
        unsigned int p01 = __builtin_amdgcn_perm(x1.u + 0x8000u, x0.u + 0x8000u, 0x07060302u);
        unsigned int p23 = __builtin_amdgcn_perm(x3.u + 0x8000u, x2.u + 0x8000u, 0x07060302u);
        *(uint2*)&P[m16 * 40 + 16 * i + quad * 4] = make_uint2(p01, p23);
      }

      // PV: O[c][q] += bg[c][k] · P[k][q]; A already in registers
      bf16x8 Pf = *(const bf16x8*)&P[m16 * 40 + quad * 8];
#pragma unroll
      for (int t = 0; t < 4; ++t)
        O[t] = __builtin_amdgcn_mfma_f32_16x16x32_bf16(Apv[t], Pf, O[t], 0, 0, 0);
    }

    // ---- merge 4 K-splits + scatter epilogue (mO aliases staging) ----
    __syncthreads();
    float* mO = (float*)smem;   // [4ks][64c][18]
    if (quad == 0) mL[ks * 16 + m16] = l_run;
#pragma unroll
    for (int t = 0; t < 4; ++t)
#pragma unroll
      for (int rr = 0; rr < 4; ++rr)
        mO[(ks * 64 + 16 * t + quad * 4 + rr) * 18 + m16] = O[t][rr];
    __syncthreads();

#pragma unroll
    for (int rep = 0; rep < 4; ++rep) {
      int e = rep * 256 + tid;         // 0..1023 = c*16 + q
      int c = e >> 4, q = e & 15;
      int qi = idxb[min(q0 + q, cnt - 1)];
      float L = mL[q] + mL[16 + q] + mL[32 + q] + mL[48 + q];
      float acc = mO[(0 * 64 + c) * 18 + q] + mO[(1 * 64 + c) * 18 + q] +
                  mO[(2 * 64 + c) * 18 + q] + mO[(3 * 64 + c) * 18 + q];
      outB[(size_t)c * HWN + qi] = acc / L;   // masked cols: out = attended exactly
    }
  }
}

extern "C" void kernel_launch(void* const* d_in, const int* in_sizes, int n_in,
                              void* d_out, int out_size, void* d_ws, size_t ws_size,
                              hipStream_t stream) {
  const float* background = (const float*)d_in[0];
  const float* foreground = (const float*)d_in[1];
  const float* mask       = (const float*)d_in[2];
  float* out = (float*)d_out;
  int* cnt = (int*)d_ws;              // 4 ints
  int* idx = (int*)d_ws + 16;         // [4][4096] ints (64 KB)
  // out = fg everywhere; masked columns fully overwritten by attn scatter
  hipMemcpyAsync(out, foreground, (size_t)4 * CC * HWN * sizeof(float),
                 hipMemcpyDeviceToDevice, stream);
  prep_kernel<<<512, 256, 0, stream>>>(background, foreground);
  compact_kernel<<<4, 1024, 0, stream>>>(mask, cnt, idx);
  attn_kernel<<<512, 256, 0, stream>>>(cnt, idx, out);
}

// Round 8
// 123.359 us; speedup vs baseline: 1.8925x; 1.1243x over previous
//
#include <hip/hip_runtime.h>
#include <math.h>

#define CC 64
#define HWN 4096
#define QB 64            // queries per block (4 x 16-q MFMA tiles)
#define KT 32
#define NCHB 16          // chunks per wave: 2048-key half / 4 waves / 32

typedef __attribute__((ext_vector_type(8))) short bf16x8;
typedef __attribute__((ext_vector_type(4))) float f32x4;

// precomputed bf16 operand layouts (fully rewritten by prep_kernel every launch)
__device__ __align__(16) unsigned short g_bgT[4][HWN][CC];  // (bg*sb)^T  [b][k][c]
__device__ __align__(16) unsigned short g_bgN[4][CC][HWN];  // bf16(bg)   [b][c][k]
__device__ __align__(16) unsigned short g_fgT[4][HWN][CC];  // (fg*sf)^T  [b][q][c]
// cross-block K-split partials
__device__ __align__(16) float g_pO[2][4][CC][HWN];         // [kh][b][c][qslot]
__device__ __align__(16) float g_pL[2][4][HWN];             // [kh][b][qslot]

static __device__ __forceinline__ unsigned int f2bf(float x) {   // RNE
  union { float f; unsigned int u; } v; v.f = x;
  return (v.u + 0x7fffu + ((v.u >> 16) & 1u)) >> 16;
}
static __device__ __forceinline__ unsigned int packbf(float lo, float hi) {
  return f2bf(lo) | (f2bf(hi) << 16);
}

// ---- prep: fused column norms + bf16 operand layouts (verified r3) ----
__global__ __launch_bounds__(256) void prep_kernel(const float* __restrict__ bg,
                                                   const float* __restrict__ fg) {
  __shared__ float lds[64 * 65];   // [k][c], stride 65 (2-way banks)
  const int bid = blockIdx.x;
  const int kt = bid & 63, b = (bid >> 6) & 3, which = bid >> 8;
  const float* src = (which ? fg : bg) + (size_t)b * CC * HWN + kt * 64;
  const int tid = threadIdx.x;

  {
    int c = tid >> 2, k0 = (tid & 3) * 16;
#pragma unroll
    for (int j4 = 0; j4 < 4; ++j4) {
      float4 v = *(const float4*)(src + (size_t)c * HWN + k0 + 4 * j4);
      lds[(k0 + 4 * j4 + 0) * 65 + c] = v.x;
      lds[(k0 + 4 * j4 + 1) * 65 + c] = v.y;
      lds[(k0 + 4 * j4 + 2) * 65 + c] = v.z;
      lds[(k0 + 4 * j4 + 3) * 65 + c] = v.w;
    }
  }
  __syncthreads();

  const int k = tid >> 2, u = tid & 3;
  float ss = 0.f;
#pragma unroll
  for (int j = 0; j < 16; ++j) {
    float v = lds[k * 65 + u * 16 + j];
    ss = fmaf(v, v, ss);
  }
  ss += __shfl_xor(ss, 1, 64);
  ss += __shfl_xor(ss, 2, 64);
  const float s = 1.0f / fmaxf(sqrtf(ss), 1e-12f);

  {
    unsigned int* gT32 = (unsigned int*)(which ? &g_fgT[0][0][0] : &g_bgT[0][0][0]);
    size_t R = (size_t)b * HWN + kt * 64 + k;
    unsigned int w8[8];
#pragma unroll
    for (int i = 0; i < 8; ++i) {
      int c2 = u * 16 + 2 * i;
      w8[i] = packbf(lds[k * 65 + c2] * s, lds[k * 65 + c2 + 1] * s);
    }
    *(uint4*)&gT32[R * 32 + u * 8]     = make_uint4(w8[0], w8[1], w8[2], w8[3]);
    *(uint4*)&gT32[R * 32 + u * 8 + 4] = make_uint4(w8[4], w8[5], w8[6], w8[7]);
  }

  if (which == 0) {
    unsigned int* gN32 = (unsigned int*)&g_bgN[0][0][0];
    int cN = tid >> 2, vN = tid & 3;
    unsigned int n8[8];
#pragma unroll
    for (int i = 0; i < 8; ++i) {
      int kk = vN * 16 + 2 * i;
      n8[i] = packbf(lds[kk * 65 + cN], lds[(kk + 1) * 65 + cN]);
    }
    size_t RN = ((size_t)b * CC + cN) * (HWN / 2) + kt * 32 + vN * 8;
    *(uint4*)&gN32[RN]     = make_uint4(n8[0], n8[1], n8[2], n8[3]);
    *(uint4*)&gN32[RN + 4] = make_uint4(n8[4], n8[5], n8[6], n8[7]);
  }
}

// ---- compact: deterministic prefix-sum of binary mask -> sorted index list ----
__global__ __launch_bounds__(1024) void compact_kernel(const float* __restrict__ mask,
                                                       int* __restrict__ cnt,
                                                       int* __restrict__ idx) {
  __shared__ int wsum[16], wbase[16];
  const int b = blockIdx.x;
  const int tid = threadIdx.x;
  const int lane = tid & 63, wv = tid >> 6;
  float4 m = *(const float4*)(mask + (b << 12) + tid * 4);
  const int p0 = m.x > 0.5f, p1 = m.y > 0.5f, p2 = m.z > 0.5f, p3 = m.w > 0.5f;
  const int ls = p0 + p1 + p2 + p3;
  int s = ls;
#pragma unroll
  for (int off = 1; off < 64; off <<= 1) {
    int v = __shfl_up(s, off, 64);
    if (lane >= off) s += v;
  }
  if (lane == 63) wsum[wv] = s;
  __syncthreads();
  if (tid == 0) {
    int acc = 0;
#pragma unroll
    for (int i = 0; i < 16; ++i) { wbase[i] = acc; acc += wsum[i]; }
    cnt[b] = acc;
  }
  __syncthreads();
  int base = wbase[wv] + s - ls;
  int* ib = idx + (b << 12);
  const int q = tid * 4;
  if (p0) ib[base++] = q;
  if (p1) ib[base++] = q + 1;
  if (p2) ib[base++] = q + 2;
  if (p3) ib[base++] = q + 3;
}

// ---- flash attention: 256 blocks = b(XCD-pinned) x 32 qtiles x 2 khalves ----
// 256 thr = 4 waves (in-block K-split), 64 q per block, 16 chunks of 32 keys.
// LDS: [0,32768)  bgT dbuf: 2 x [4ks][32k][64c] swizzled
//      [32768,53248) P per wave [64q][40k] ushort
//      [53248,54272) mL [4ks][64q] f32
//      merge aliases [0,34816) as mO [4ks][64c][34] per 32-q pass
#define SMEM_BYTES 54272
__global__ __launch_bounds__(256, 1) void attn_kernel(const int* __restrict__ cntp,
                                                      const int* __restrict__ idx) {
  const int id = blockIdx.x;
  const int b = (id >> 1) & 3;          // batch pinned to one XCD pair
  const int r0 = ((id >> 3) << 1) | (id & 1);   // 0..63 per batch
  const int cnt = cntp[b];
  const int nunits = ((cnt + 63) >> 6) << 1;    // ntiles * 2 khalves

  __shared__ __align__(16) char smem[SMEM_BYTES];
  const int tid = threadIdx.x;
  const int lane = tid & 63;
  const int ks = tid >> 6;              // wave = in-block K-split 0..3
  const int m16 = lane & 15;
  const int quad = lane >> 4;
  const int* idxb = idx + (b << 12);

  // staging swizzle (4 x 16B granules per lane per chunk), key-base added later
  const unsigned short* src_base[4];
#pragma unroll
  for (int t = 0; t < 4; ++t) {
    int uT = t * 64 + lane;
    int kk = uT >> 3, j = (uT & 7) ^ (kk & 7);
    src_base[t] = &g_bgT[b][kk][j * 8];
  }
  unsigned short* P = (unsigned short*)(smem + 32768 + ks * 5120);  // [64q][40k]
  float* mL = (float*)(smem + 53248);

  for (int r = r0; r < nunits; r += 64) {
    const int q0 = (r >> 1) * QB;
    const int kh = r & 1;
    const int kbase = kh * 2048 + ks * 512;

    // fg B-fragments for 4 q-tiles (gathered compacted rows)
    bf16x8 Bf[4][2];
#pragma unroll
    for (int qt = 0; qt < 4; ++qt) {
      int qrow = idxb[min(q0 + qt * 16 + m16, cnt - 1)];
      Bf[qt][0] = *(const bf16x8*)&g_fgT[b][qrow][quad * 8];
      Bf[qt][1] = *(const bf16x8*)&g_fgT[b][qrow][32 + quad * 8];
    }

    float l_run[4] = {0.f, 0.f, 0.f, 0.f};
    f32x4 O[4][4];   // [ctile][qtile]
#pragma unroll
    for (int t = 0; t < 4; ++t)
#pragma unroll
      for (int qt = 0; qt < 4; ++qt) O[t][qt] = (f32x4){0.f, 0.f, 0.f, 0.f};

    __syncthreads();   // prev unit's mO reads (alias staging) done
    // prologue fetch
    {
      char* base = smem + ks * 4096;
#pragma unroll
      for (int t = 0; t < 4; ++t)
        __builtin_amdgcn_global_load_lds(
            (const __attribute__((address_space(1))) unsigned int*)(src_base[t] + (size_t)kbase * CC),
            (__attribute__((address_space(3))) unsigned int*)(base + t * 1024), 16, 0, 0);
    }

    for (int it = 0; it < NCHB; ++it) {
      __syncthreads();               // drains fetch(it); buffer (it&1) valid
      const int kb = kbase + it * KT;

      // PV A-operands first: their waitcnt is vmcnt(4), leaving the LDS
      // prefetch below in flight; they land during score MFMA + softmax.
      bf16x8 Apv[4];
#pragma unroll
      for (int t = 0; t < 4; ++t)
        Apv[t] = *(const bf16x8*)&g_bgN[b][16 * t + m16][kb + quad * 8];

      if (it + 1 < NCHB) {           // prefetch next chunk into other buffer
        char* base = smem + ((it + 1) & 1) * 16384 + ks * 4096;
#pragma unroll
        for (int t = 0; t < 4; ++t)
          __builtin_amdgcn_global_load_lds(
              (const __attribute__((address_space(1))) unsigned int*)(src_base[t] + (size_t)(kb + KT) * CC),
              (__attribute__((address_space(3))) unsigned int*)(base + t * 1024), 16, 0, 0);
      }

      const char* baseT = smem + (it & 1) * 16384 + ks * 4096;

      // scores S[32k][64q] + fixed-max softmax (|cos|<=1: p=exp(s-1)) + P pack
#pragma unroll
      for (int i = 0; i < 2; ++i) {
        int kk = 16 * i + m16;
        bf16x8 A0 = *(const bf16x8*)(baseT + kk * 128 + ((quad ^ (kk & 7)) * 16));
        bf16x8 A1 = *(const bf16x8*)(baseT + kk * 128 + (((4 + quad) ^ (kk & 7)) * 16));
#pragma unroll
        for (int qt = 0; qt < 4; ++qt) {
          f32x4 acc = {0.f, 0.f, 0.f, 0.f};
          acc = __builtin_amdgcn_mfma_f32_16x16x32_bf16(A0, Bf[qt][0], acc, 0, 0, 0);
          acc = __builtin_amdgcn_mfma_f32_16x16x32_bf16(A1, Bf[qt][1], acc, 0, 0, 0);
          float pe0 = __expf(acc[0] - 1.0f), pe1 = __expf(acc[1] - 1.0f);
          float pe2 = __expf(acc[2] - 1.0f), pe3 = __expf(acc[3] - 1.0f);
          l_run[qt] += (pe0 + pe1) + (pe2 + pe3);   // cross-lane reduce deferred
          union { float f; unsigned int u; } x0, x1, x2, x3;
          x0.f = pe0; x1.f = pe1; x2.f = pe2; x3.f = pe3;
          unsigned int p01 = __builtin_amdgcn_perm(x1.u + 0x8000u, x0.u + 0x8000u, 0x07060302u);
          unsigned int p23 = __builtin_amdgcn_perm(x3.u + 0x8000u, x2.u + 0x8000u, 0x07060302u);
          *(uint2*)&P[(qt * 16 + m16) * 40 + 16 * i + quad * 4] = make_uint2(p01, p23);
        }
      }

      // PV: O[c][q] += bg[c][k] · P[k][q]  (wave-private P, no barrier)
#pragma unroll
      for (int qt = 0; qt < 4; ++qt) {
        bf16x8 Pf = *(const bf16x8*)&P[(qt * 16 + m16) * 40 + quad * 8];
#pragma unroll
        for (int t = 0; t < 4; ++t)
          O[t][qt] = __builtin_amdgcn_mfma_f32_16x16x32_bf16(Apv[t], Pf, O[t][qt], 0, 0, 0);
      }
    }

    // l: reduce over quads once per unit
#pragma unroll
    for (int qt = 0; qt < 4; ++qt) {
      float l = l_run[qt];
      l += __shfl_xor(l, 16, 64);
      l += __shfl_xor(l, 32, 64);
      if (quad == 0) mL[ks * 64 + qt * 16 + m16] = l;
    }

    // merge 4 in-block K-splits via LDS, 2 passes of 32 q; store partials
    float* mO = (float*)smem;   // [4ks][64c][34]
#pragma unroll
    for (int h = 0; h < 2; ++h) {
      __syncthreads();
#pragma unroll
      for (int t = 0; t < 4; ++t)
#pragma unroll
        for (int j = 0; j < 2; ++j)
#pragma unroll
          for (int rr = 0; rr < 4; ++rr)
            mO[(ks * 64 + 16 * t + quad * 4 + rr) * 34 + j * 16 + m16] = O[t][2 * h + j][rr];
      __syncthreads();
#pragma unroll
      for (int rep = 0; rep < 8; ++rep) {
        int e = rep * 256 + tid;       // 0..2047 = c*32 + q
        int c = e >> 5, q = e & 31;
        float acc = mO[(0 * 64 + c) * 34 + q] + mO[(1 * 64 + c) * 34 + q] +
                    mO[(2 * 64 + c) * 34 + q] + mO[(3 * 64 + c) * 34 + q];
        g_pO[kh][b][c][q0 + h * 32 + q] = acc;
      }
    }
    if (tid < 64)
      g_pL[kh][b][q0 + tid] = mL[tid] + mL[64 + tid] + mL[128 + tid] + mL[192 + tid];
  }
}

// ---- merge the 2 cross-block K-halves + scatter to output ----
__global__ __launch_bounds__(256) void merge_kernel(const int* __restrict__ cntp,
                                                    const int* __restrict__ idx,
                                                    float* __restrict__ out) {
  int t = blockIdx.x * 256 + threadIdx.x;   // 0..16383
  int b = t >> 12, qs = t & 4095;
  if (qs >= cntp[b]) return;
  int qi = idx[(b << 12) + qs];
  float inv = 1.0f / (g_pL[0][b][qs] + g_pL[1][b][qs]);
  float* outB = out + (size_t)b * CC * HWN;
#pragma unroll 8
  for (int c = 0; c < CC; ++c)
    outB[(size_t)c * HWN + qi] = (g_pO[0][b][c][qs] + g_pO[1][b][c][qs]) * inv;
}

extern "C" void kernel_launch(void* const* d_in, const int* in_sizes, int n_in,
                              void* d_out, int out_size, void* d_ws, size_t ws_size,
                              hipStream_t stream) {
  const float* background = (const float*)d_in[0];
  const float* foreground = (const float*)d_in[1];
  const float* mask       = (const float*)d_in[2];
  float* out = (float*)d_out;
  int* cnt = (int*)d_ws;              // 4 ints
  int* idx = (int*)d_ws + 16;         // [4][4096] ints (64 KB)
  // out = fg everywhere; masked columns fully overwritten by merge scatter
  hipMemcpyAsync(out, foreground, (size_t)4 * CC * HWN * sizeof(float),
                 hipMemcpyDeviceToDevice, stream);
  prep_kernel<<<512, 256, 0, stream>>>(background, foreground);
  compact_kernel<<<4, 1024, 0, stream>>>(mask, cnt, idx);
  attn_kernel<<<256, 256, 0, stream>>>(cnt, idx);
  merge_kernel<<<64, 256, 0, stream>>>(cnt, idx, out);
}